// Round 10
// baseline (305.443 us; speedup 1.0000x reference)
//
#include <hip/hip_runtime.h>
#include <math.h>

#define TT 16
#define BB 32
#define NN 256
#define DD 128
#define NSTEPS 5
#define SKIPF 0.3f
#define EPSF 1e-8f
// truncated scan: timesteps t < T0 contribute <= ~2e-5 to A_15 (attn rows
// normalized; 0.7*sum_{t<T0} 0.3^(15-t)) -- 400x below tolerance. Verified
// R18: absmax unchanged at 0.0078125.
#define T0 7
#define TBLIVE ((TT - T0) * BB)    // 288 live (t,b) pairs

// R12: f16 packed-math gram. R15: 64x64 wave tiles (issue-bound 94%).
// R16: MFMA norms. R17: FAILED cross-XCD barrier fusion (45us/barrier).
// R18: truncated scan t>=7: 304.8us, gram2 91us.
// R19 (this round): dispatch compression 12 -> 9 + in-gram2 norms.
//   - gram2 squares its resident Bf frags (64 pk_mul) + 16 MFMA -> invn
//     in-block; invnH buffer/traffic and k_prep's norms machinery deleted.
//   - k_xw = pure f16 convert + wprep (blockIdx branch).
//   - scanlast + hTinit merged (blockIdx branch).
//   - fc: grid 32 block-reduction, no atomics, no memset.
//   Calibrates dispatch-boundary cost (~150us unexplained across 11
//   boundaries) for a possible grid-32 fused GRU next round.

typedef __attribute__((ext_vector_type(8))) short bf16x8;
typedef __attribute__((ext_vector_type(4))) float f32x4;
typedef __attribute__((ext_vector_type(8))) _Float16 half8;
typedef __attribute__((ext_vector_type(2))) _Float16 h2;

__device__ __forceinline__ unsigned short f2bf(float f) {
    union { float f; unsigned u; } v; v.f = f;
    unsigned r = (v.u + 0x7FFF + ((v.u >> 16) & 1)) >> 16;
    return (unsigned short)r;
}
__device__ __forceinline__ float bf2f(unsigned short u) {
    union { unsigned u; float f; } v; v.u = ((unsigned)u) << 16; return v.f;
}
__device__ __forceinline__ unsigned pack2(unsigned short a, unsigned short b) {
    return (unsigned)a | ((unsigned)b << 16);
}
// packed f32->f16 convert (RTZ), 1 inst for 2 elems
__device__ __forceinline__ unsigned pkrtz(float a, float b) {
    unsigned r;
    asm("v_cvt_pkrtz_f16_f32 %0, %1, %2" : "=v"(r) : "v"(a), "v"(b));
    return r;
}
__device__ __forceinline__ h2 u2h(unsigned u) {
    union { unsigned u; h2 h; } v; v.u = u; return v.h;
}
__device__ __forceinline__ float sigmoidf_(float x) {
    return 1.0f / (1.0f + __expf(-x));
}
__device__ __forceinline__ float tanhf_(float x) {
    return 1.0f - 2.0f / (__expf(2.0f * x) + 1.0f);
}

// ---------------------------------------------------------------------------
// xw: blocks 0..TBLIVE-1: xh = f16(x) for live tb (streaming convert).
//     blocks TBLIVE..TBLIVE+127: bf16-transposed GRU weights (old wprep).
// ---------------------------------------------------------------------------
__global__ __launch_bounds__(256) void k_xw(const float* __restrict__ x,
                                            const float* __restrict__ Wa,
                                            const float* __restrict__ Wr,
                                            const float* __restrict__ Wz,
                                            const float* __restrict__ Wh,
                                            unsigned short* __restrict__ xh,
                                            unsigned short* __restrict__ WaT,
                                            unsigned short* __restrict__ WrT,
                                            unsigned short* __restrict__ WzT,
                                            unsigned short* __restrict__ WhT) {
    int bid = blockIdx.x;
    int tid = threadIdx.x;
    if (bid < TBLIVE) {
        int tb = T0 * BB + bid;
        const float* xb = x + ((size_t)tb << 15);
        unsigned short* xhb = xh + ((size_t)tb << 15);
        #pragma unroll
        for (int it = 0; it < 16; ++it) {
            int flat = (it << 11) + (tid << 3);
            float4 a = *(const float4*)(xb + flat);
            float4 b = *(const float4*)(xb + flat + 4);
            uint4 o;
            o.x = pkrtz(a.x, a.y); o.y = pkrtz(a.z, a.w);
            o.z = pkrtz(b.x, b.y); o.w = pkrtz(b.z, b.w);
            *(uint4*)(xhb + flat) = o;
        }
    } else {
        int idx = (bid - TBLIVE) * 256 + tid;     // 0..32767
        if (idx < 16384) {
            int dout = idx >> 7, din = idx & 127;
            WaT[idx] = f2bf(Wa[(din << 7) + dout]);
        }
        {
            int dout = idx >> 8, dk = idx & 255;
            WrT[idx] = f2bf(Wr[(dk << 7) + dout]);
            WzT[idx] = f2bf(Wz[(dk << 7) + dout]);
            WhT[idx] = f2bf(Wh[(dk << 7) + dout]);
        }
    }
}

// ---------------------------------------------------------------------------
// gram2 (f16 packed, 64x64 wave tiles, IN-BLOCK norms):
//   attn_t = 0.7*rownorm(relu(sum_h D_h X W2_h X^T D_h)).
// grid = 4 rg x TBLIVE = 1152 blocks, 256 threads, LDS 21.5 KB.
// New: w^2 table computed from Wgl in-block (8KB L2); invn computed from
// the wave's resident Bf frags (squared, 16 MFMA vs w^2) -> ivS. The Bf
// layout (row=col index, k=d) IS the A-operand layout for the norms MFMA;
// D (col=lane&15 -> h, row=quad*4+r) matches ivS[h][row] write.
// ---------------------------------------------------------------------------
__global__ __launch_bounds__(256, 2) void k_gram2(const unsigned short* __restrict__ xhp,
                                                  const float* __restrict__ Wgl,
                                                  unsigned short* __restrict__ attn) {
    int bid = blockIdx.x;
    int rg = bid / TBLIVE;              // 0..3
    int tb = T0 * BB + (bid - rg * TBLIVE);
    int n0 = rg << 6;
    int tid = threadIdx.x;
    int wave = tid >> 6, lane = tid & 63;
    int m16 = lane & 15, quad = lane >> 4;
    int wcol = wave << 6;

    __shared__ unsigned wS[16 * 64];     // 4 KB: w^2 packed f16 pairs [h][d/2]
    __shared__ unsigned ivS[16 * 256];   // 16 KB: invn dup-f16 [h][n]
    __shared__ float rsum[4][64];        // 1 KB

    const unsigned short* Xb = xhp + ((size_t)tb << 15);

    // ---- stage wS = f16(w^2) from Wgl (one-time, 4 u32/thread) ----
    #pragma unroll
    for (int k = 0; k < 4; ++k) {
        int idx = (tid << 2) + k;        // 0..1023 ; h = idx>>6, j = idx&63
        float2 wv = *(const float2*)(Wgl + ((idx >> 6) << 7) + ((idx & 63) << 1));
        wS[idx] = pkrtz(wv.x * wv.x, wv.y * wv.y);
    }

    // ---- resident raw fragments (packed f16) ----
    half8 Bf[4][4];                     // [ks][cb] = 64 VGPR (wave's 64 cols)
    #pragma unroll
    for (int ks = 0; ks < 4; ++ks)
        #pragma unroll
        for (int cb = 0; cb < 4; ++cb)
            Bf[ks][cb] = *(const half8*)(Xb + ((wcol + (cb << 4) + m16) << 7) + (ks << 5) + (quad << 3));

    half8 Af[4][4];                     // [rb][ks] = 64 VGPR (block's 64 rows)
    #pragma unroll
    for (int rb = 0; rb < 4; ++rb)
        #pragma unroll
        for (int ks = 0; ks < 4; ++ks)
            Af[rb][ks] = *(const half8*)(Xb + ((n0 + (rb << 4) + m16) << 7) + (ks << 5) + (quad << 3));

    f32x4 att[4][4];
    #pragma unroll
    for (int rb = 0; rb < 4; ++rb)
        #pragma unroll
        for (int cb = 0; cb < 4; ++cb) att[rb][cb] = (f32x4){0.f, 0.f, 0.f, 0.f};

    __syncthreads();   // wS staged

    union H8 { half8 v; h2 p[4]; };

    // ---- in-block norms for this wave's 64 rows (= its B cols) ----
    {
        half8 w2f[4];
        #pragma unroll
        for (int ks = 0; ks < 4; ++ks)
            w2f[ks] = *(const half8*)((const unsigned short*)wS + (m16 << 7) + (ks << 5) + (quad << 3));
        #pragma unroll
        for (int cb = 0; cb < 4; ++cb) {
            f32x4 nacc = (f32x4){0.f, 0.f, 0.f, 0.f};
            #pragma unroll
            for (int ks = 0; ks < 4; ++ks) {
                H8 bb; bb.v = Bf[ks][cb];
                H8 sq;
                sq.p[0] = bb.p[0] * bb.p[0];
                sq.p[1] = bb.p[1] * bb.p[1];
                sq.p[2] = bb.p[2] * bb.p[2];
                sq.p[3] = bb.p[3] * bb.p[3];
                nacc = __builtin_amdgcn_mfma_f32_16x16x32_f16(sq.v, w2f[ks], nacc, 0, 0, 0);
            }
            #pragma unroll
            for (int r = 0; r < 4; ++r) {
                float inv = 1.0f / (sqrtf(nacc[r]) + EPSF);
                ivS[(m16 << 8) + wcol + (cb << 4) + (quad << 2) + r] = pkrtz(inv, inv);
            }
        }
    }
    __syncthreads();   // ivS ready

    #pragma unroll 1
    for (int h = 0; h < 16; ++h) {
        const unsigned* ivh = ivS + (h << 8);
        h2 ivr[4], ivc[4];
        #pragma unroll
        for (int rb = 0; rb < 4; ++rb) ivr[rb] = u2h(ivh[n0 + (rb << 4) + m16]);
        #pragma unroll
        for (int cb = 0; cb < 4; ++cb) ivc[cb] = u2h(ivh[wcol + (cb << 4) + m16]);

        #pragma unroll
        for (int ks = 0; ks < 4; ++ks) {
            uint4 wu = *(const uint4*)(wS + (h << 6) + (ks << 4) + (quad << 2));
            h2 w0 = u2h(wu.x), w1 = u2h(wu.y), w2 = u2h(wu.z), w3 = u2h(wu.w);

            H8 afr[4];
            #pragma unroll
            for (int rb = 0; rb < 4; ++rb) {
                H8 a; a.v = Af[rb][ks];
                h2 s = ivr[rb];
                afr[rb].p[0] = a.p[0] * (w0 * s);
                afr[rb].p[1] = a.p[1] * (w1 * s);
                afr[rb].p[2] = a.p[2] * (w2 * s);
                afr[rb].p[3] = a.p[3] * (w3 * s);
            }
            #pragma unroll
            for (int cb = 0; cb < 4; ++cb) {
                H8 b; b.v = Bf[ks][cb];
                H8 bf;
                bf.p[0] = b.p[0] * ivc[cb];
                bf.p[1] = b.p[1] * ivc[cb];
                bf.p[2] = b.p[2] * ivc[cb];
                bf.p[3] = b.p[3] * ivc[cb];
                #pragma unroll
                for (int rb = 0; rb < 4; ++rb)
                    att[rb][cb] = __builtin_amdgcn_mfma_f32_16x16x32_f16(afr[rb].v, bf.v, att[rb][cb], 0, 0, 0);
            }
        }
    }

    // relu + rowsum + normalize (x0.7) -> bf16 attn  (relu(S)/16 trick: +16eps)
    float rs[4][4];
    #pragma unroll
    for (int rb = 0; rb < 4; ++rb)
        #pragma unroll
        for (int r = 0; r < 4; ++r) {
            float s = 0.f;
            #pragma unroll
            for (int cb = 0; cb < 4; ++cb) {
                float v = fmaxf(att[rb][cb][r], 0.0f);
                att[rb][cb][r] = v;
                s += v;
            }
            rs[rb][r] = s;
        }
    #pragma unroll
    for (int m = 1; m < 16; m <<= 1)
        #pragma unroll
        for (int rb = 0; rb < 4; ++rb)
            #pragma unroll
            for (int r = 0; r < 4; ++r)
                rs[rb][r] += __shfl_xor(rs[rb][r], m, 64);
    if (m16 == 0) {
        #pragma unroll
        for (int rb = 0; rb < 4; ++rb)
            #pragma unroll
            for (int r = 0; r < 4; ++r)
                rsum[wave][(rb << 4) + (quad << 2) + r] = rs[rb][r];
    }
    __syncthreads();

    unsigned short* outb = attn + ((size_t)tb << 16);
    #pragma unroll
    for (int rb = 0; rb < 4; ++rb) {
        #pragma unroll
        for (int r = 0; r < 4; ++r) {
            int row = (rb << 4) + (quad << 2) + r;
            float tot = rsum[0][row] + rsum[1][row] + rsum[2][row] + rsum[3][row];
            float inv = (1.0f - SKIPF) / (tot + 16.0f * EPSF);
            #pragma unroll
            for (int cb = 0; cb < 4; ++cb) {
                int col = wcol + (cb << 4) + m16;
                outb[((size_t)(n0 + row) << 8) + col] = f2bf(att[rb][cb][r] * inv);
            }
        }
    }
}

// ---------------------------------------------------------------------------
// scanh: blocks 0..2047: scan (a = supports*0.3^T0; a = 0.3a + attn_t,
//        t = T0..15) -> Afin bf16. blocks 2048..3071: hTinit transpose.
// ---------------------------------------------------------------------------
__global__ __launch_bounds__(256) void k_scanh(const float* __restrict__ supports,
                                               const unsigned short* __restrict__ AttA,
                                               const float* __restrict__ x15,
                                               unsigned short* __restrict__ Afin,
                                               unsigned short* __restrict__ hT) {
    __shared__ float tl[32][33];
    int bid = blockIdx.x;
    int tid = threadIdx.x;
    if (bid < 2048) {
        size_t flat = ((size_t)bid * 256 + tid) * 4;
        float4 s4 = *(const float4*)(supports + flat);
        const float s7 = SKIPF * SKIPF * SKIPF * SKIPF * SKIPF * SKIPF * SKIPF; // 0.3^T0
        float a0 = s4.x * s7, a1 = s4.y * s7, a2 = s4.z * s7, a3 = s4.w * s7;
        #pragma unroll
        for (int t = T0; t < TT; ++t) {
            const unsigned short* p = AttA + ((size_t)t << 21) + flat;
            uint2 u = *(const uint2*)p;
            a0 = SKIPF * a0 + bf2f((unsigned short)(u.x & 0xffff));
            a1 = SKIPF * a1 + bf2f((unsigned short)(u.x >> 16));
            a2 = SKIPF * a2 + bf2f((unsigned short)(u.y & 0xffff));
            a3 = SKIPF * a3 + bf2f((unsigned short)(u.y >> 16));
        }
        uint2 o;
        o.x = pack2(f2bf(a0), f2bf(a1));
        o.y = pack2(f2bf(a2), f2bf(a3));
        *(uint2*)(Afin + flat) = o;
    } else {
        int b2 = bid - 2048;
        int b = b2 >> 5; int r = b2 & 31; int d0 = (r >> 3) << 5; int n0 = (r & 7) << 5;
        int i = tid >> 5, j = tid & 31;
        #pragma unroll
        for (int s = 0; s < 4; ++s) {
            int nl = (s << 3) + i;
            tl[nl][j] = x15[((size_t)(b * 256 + n0 + nl) << 7) + d0 + j];
        }
        __syncthreads();
        #pragma unroll
        for (int s = 0; s < 4; ++s) {
            int dd = (s << 3) + i;
            hT[((size_t)(b * 128 + d0 + dd) << 8) + n0 + j] = f2bf(tl[j][dd]);
        }
    }
}

// ---------------------------------------------------------------------------
// step: fused GGNN/GRU step for t=15 only — VERIFIED R16 version.
// grid = 8 rg x 32 b = 256 blocks.
// ---------------------------------------------------------------------------
__global__ __launch_bounds__(256) void k_step(
    const unsigned short* __restrict__ Afin,
    const unsigned short* __restrict__ hT,
    const unsigned short* __restrict__ WaT, const float* __restrict__ ba,
    const unsigned short* __restrict__ WrT, const float* __restrict__ br,
    const unsigned short* __restrict__ WzT, const float* __restrict__ bz,
    const unsigned short* __restrict__ WhT, const float* __restrict__ bh,
    unsigned short* __restrict__ hT_o) {

    int bid = blockIdx.x;
    int b = bid & 31, rg = bid >> 5;
    int n0 = rg << 5;
    int tid = threadIdx.x;
    int wave = tid >> 6, lane = tid & 63;
    int m16 = lane & 15, quad = lane >> 4;
    int wcol = wave << 5;

    __shared__ unsigned short msgS[32 * 136];
    __shared__ unsigned short ahS[32 * 264];   // k 0..127 = a, 128..255 = h (later r*h)

    const unsigned short* hTb = hT + ((size_t)b << 15);

    // stage h-half of ahS from hT (transpose: ahS[row][128+d] = hT[d][n0+row])
    #pragma unroll
    for (int j = 0; j < 16; ++j) {
        int idx = (j << 8) + tid;            // 0..4095
        int d = idx >> 5, row = idx & 31;
        ahS[row * 264 + 128 + d] = hTb[((size_t)d << 8) + n0 + row];
    }

    // ---- bmm: msg = A_tile @ h  (K=256) ----
    f32x4 acc[2][2];
    #pragma unroll
    for (int rb = 0; rb < 2; ++rb)
        #pragma unroll
        for (int cb = 0; cb < 2; ++cb) acc[rb][cb] = (f32x4){0.f, 0.f, 0.f, 0.f};

    const unsigned short* Ab = Afin + ((size_t)b << 16) + ((size_t)n0 << 8);
    #pragma unroll 2
    for (int ks = 0; ks < 8; ++ks) {
        bf16x8 af[2], bf[2];
        #pragma unroll
        for (int rb = 0; rb < 2; ++rb)
            af[rb] = *(const bf16x8*)(Ab + (((rb << 4) + m16) << 8) + (ks << 5) + (quad << 3));
        #pragma unroll
        for (int cb = 0; cb < 2; ++cb)
            bf[cb] = *(const bf16x8*)(hTb + ((wcol + (cb << 4) + m16) << 8) + (ks << 5) + (quad << 3));
        #pragma unroll
        for (int rb = 0; rb < 2; ++rb)
            #pragma unroll
            for (int cb = 0; cb < 2; ++cb)
                acc[rb][cb] = __builtin_amdgcn_mfma_f32_16x16x32_bf16(af[rb], bf[cb], acc[rb][cb], 0, 0, 0);
    }
    #pragma unroll
    for (int rb = 0; rb < 2; ++rb)
        #pragma unroll
        for (int cb = 0; cb < 2; ++cb)
            #pragma unroll
            for (int r = 0; r < 4; ++r)
                msgS[((rb << 4) + (quad << 2) + r) * 136 + wcol + (cb << 4) + m16] = f2bf(acc[rb][cb][r]);
    __syncthreads();   // covers h-half staging too

    // ---- a = msg @ Wa + ba ----
    #pragma unroll
    for (int rb = 0; rb < 2; ++rb)
        #pragma unroll
        for (int cb = 0; cb < 2; ++cb) acc[rb][cb] = (f32x4){0.f, 0.f, 0.f, 0.f};
    #pragma unroll
    for (int ks = 0; ks < 4; ++ks) {
        bf16x8 af[2], bf[2];
        #pragma unroll
        for (int rb = 0; rb < 2; ++rb)
            af[rb] = *(const bf16x8*)(msgS + ((rb << 4) + m16) * 136 + (ks << 5) + (quad << 3));
        #pragma unroll
        for (int cb = 0; cb < 2; ++cb)
            bf[cb] = *(const bf16x8*)(WaT + ((wcol + (cb << 4) + m16) << 7) + (ks << 5) + (quad << 3));
        #pragma unroll
        for (int rb = 0; rb < 2; ++rb)
            #pragma unroll
            for (int cb = 0; cb < 2; ++cb)
                acc[rb][cb] = __builtin_amdgcn_mfma_f32_16x16x32_bf16(af[rb], bf[cb], acc[rb][cb], 0, 0, 0);
    }
    {
        float bav[2];
        #pragma unroll
        for (int cb = 0; cb < 2; ++cb) bav[cb] = ba[wcol + (cb << 4) + m16];
        #pragma unroll
        for (int rb = 0; rb < 2; ++rb)
            #pragma unroll
            for (int cb = 0; cb < 2; ++cb)
                #pragma unroll
                for (int r = 0; r < 4; ++r)
                    ahS[((rb << 4) + (quad << 2) + r) * 264 + wcol + (cb << 4) + m16] =
                        f2bf(acc[rb][cb][r] + bav[cb]);
    }
    __syncthreads();

    // h_old (for r*h and final update): uint2 = 4 consecutive n at fixed col
    float hv[2][2][4];
    #pragma unroll
    for (int rb = 0; rb < 2; ++rb)
        #pragma unroll
        for (int cb = 0; cb < 2; ++cb) {
            int col = wcol + (cb << 4) + m16;
            uint2 u = *(const uint2*)(hTb + ((size_t)col << 8) + n0 + (rb << 4) + (quad << 2));
            hv[rb][cb][0] = bf2f((unsigned short)(u.x & 0xffff));
            hv[rb][cb][1] = bf2f((unsigned short)(u.x >> 16));
            hv[rb][cb][2] = bf2f((unsigned short)(u.y & 0xffff));
            hv[rb][cb][3] = bf2f((unsigned short)(u.y >> 16));
        }

    // ---- r and z ----
    f32x4 racc[2][2], zacc[2][2];
    #pragma unroll
    for (int rb = 0; rb < 2; ++rb)
        #pragma unroll
        for (int cb = 0; cb < 2; ++cb) {
            racc[rb][cb] = (f32x4){0.f, 0.f, 0.f, 0.f};
            zacc[rb][cb] = (f32x4){0.f, 0.f, 0.f, 0.f};
        }
    #pragma unroll 2
    for (int ks = 0; ks < 8; ++ks) {
        bf16x8 af[2], bfr[2], bfz[2];
        #pragma unroll
        for (int rb = 0; rb < 2; ++rb)
            af[rb] = *(const bf16x8*)(ahS + ((rb << 4) + m16) * 264 + (ks << 5) + (quad << 3));
        #pragma unroll
        for (int cb = 0; cb < 2; ++cb) {
            int dout = wcol + (cb << 4) + m16;
            bfr[cb] = *(const bf16x8*)(WrT + (dout << 8) + (ks << 5) + (quad << 3));
            bfz[cb] = *(const bf16x8*)(WzT + (dout << 8) + (ks << 5) + (quad << 3));
        }
        #pragma unroll
        for (int rb = 0; rb < 2; ++rb)
            #pragma unroll
            for (int cb = 0; cb < 2; ++cb) {
                racc[rb][cb] = __builtin_amdgcn_mfma_f32_16x16x32_bf16(af[rb], bfr[cb], racc[rb][cb], 0, 0, 0);
                zacc[rb][cb] = __builtin_amdgcn_mfma_f32_16x16x32_bf16(af[rb], bfz[cb], zacc[rb][cb], 0, 0, 0);
            }
    }
    float zv[2][2][4];
    {
        float brv[2], bzv[2];
        #pragma unroll
        for (int cb = 0; cb < 2; ++cb) {
            brv[cb] = br[wcol + (cb << 4) + m16];
            bzv[cb] = bz[wcol + (cb << 4) + m16];
        }
        #pragma unroll
        for (int rb = 0; rb < 2; ++rb)
            #pragma unroll
            for (int cb = 0; cb < 2; ++cb)
                #pragma unroll
                for (int r = 0; r < 4; ++r) {
                    racc[rb][cb][r] = sigmoidf_(racc[rb][cb][r] + brv[cb]);
                    zv[rb][cb][r]  = sigmoidf_(zacc[rb][cb][r] + bzv[cb]);
                }
    }
    __syncthreads();   // all ahS reads done -> safe to overwrite h-half

    #pragma unroll
    for (int rb = 0; rb < 2; ++rb)
        #pragma unroll
        for (int cb = 0; cb < 2; ++cb)
            #pragma unroll
            for (int r = 0; r < 4; ++r)
                ahS[((rb << 4) + (quad << 2) + r) * 264 + 128 + wcol + (cb << 4) + m16] =
                    f2bf(racc[rb][cb][r] * hv[rb][cb][r]);
    __syncthreads();

    // ---- h_tilde ----
    #pragma unroll
    for (int rb = 0; rb < 2; ++rb)
        #pragma unroll
        for (int cb = 0; cb < 2; ++cb) acc[rb][cb] = (f32x4){0.f, 0.f, 0.f, 0.f};
    #pragma unroll 2
    for (int ks = 0; ks < 8; ++ks) {
        bf16x8 af[2], bf[2];
        #pragma unroll
        for (int rb = 0; rb < 2; ++rb)
            af[rb] = *(const bf16x8*)(ahS + ((rb << 4) + m16) * 264 + (ks << 5) + (quad << 3));
        #pragma unroll
        for (int cb = 0; cb < 2; ++cb)
            bf[cb] = *(const bf16x8*)(WhT + ((wcol + (cb << 4) + m16) << 8) + (ks << 5) + (quad << 3));
        #pragma unroll
        for (int rb = 0; rb < 2; ++rb)
            #pragma unroll
            for (int cb = 0; cb < 2; ++cb)
                acc[rb][cb] = __builtin_amdgcn_mfma_f32_16x16x32_bf16(af[rb], bf[cb], acc[rb][cb], 0, 0, 0);
    }

    // ---- update + writes (hT only) ----
    {
        float bhv[2];
        #pragma unroll
        for (int cb = 0; cb < 2; ++cb) bhv[cb] = bh[wcol + (cb << 4) + m16];
        #pragma unroll
        for (int rb = 0; rb < 2; ++rb)
            #pragma unroll
            for (int cb = 0; cb < 2; ++cb) {
                int col = wcol + (cb << 4) + m16;
                unsigned short pk[4];
                #pragma unroll
                for (int r = 0; r < 4; ++r) {
                    float ht = tanhf_(acc[rb][cb][r] + bhv[cb]);
                    float hn = hv[rb][cb][r] + zv[rb][cb][r] * (ht - hv[rb][cb][r]);
                    pk[r] = f2bf(hn);
                }
                uint2 p;
                p.x = pack2(pk[0], pk[1]); p.y = pack2(pk[2], pk[3]);
                *(uint2*)(hT_o + ((size_t)(b * 128 + col) << 8) + n0 + (rb << 4) + (quad << 2)) = p;
            }
    }
}

// ---------------------------------------------------------------------------
// fc: grid 32 (one block per b): logits[b,c] = sum + bfc. Direct write,
// no atomics, no memset.
// ---------------------------------------------------------------------------
__global__ __launch_bounds__(256) void k_fc(const unsigned short* __restrict__ hT,
                                            const float* __restrict__ Wfc,
                                            const float* __restrict__ bfc,
                                            float* __restrict__ out) {
    int b = blockIdx.x;
    int tid = threadIdx.x;
    const unsigned short* hp = hT + ((size_t)b << 15);
    float a0 = 0.f, a1 = 0.f;
    #pragma unroll 2
    for (int it = 0; it < 16; ++it) {
        int i = (it << 11) + (tid << 3);     // linear col-major: i = d*256 + n
        int d = i >> 8, n = i & 255;
        uint4 hu = *(const uint4*)(hp + i);
        unsigned short hs[8];
        hs[0] = hu.x & 0xffff; hs[1] = hu.x >> 16;
        hs[2] = hu.y & 0xffff; hs[3] = hu.y >> 16;
        hs[4] = hu.z & 0xffff; hs[5] = hu.z >> 16;
        hs[6] = hu.w & 0xffff; hs[7] = hu.w >> 16;
        #pragma unroll
        for (int k = 0; k < 8; ++k) {
            float v = bf2f(hs[k]);
            const float2 w = *(const float2*)(Wfc + ((size_t)(n + k) * 128 + d) * 2);
            a0 = fmaf(v, w.x, a0);
            a1 = fmaf(v, w.y, a1);
        }
    }
    int wave = tid >> 6, lane = tid & 63;
    #pragma unroll
    for (int off = 32; off; off >>= 1) {
        a0 += __shfl_down(a0, off, 64);
        a1 += __shfl_down(a1, off, 64);
    }
    __shared__ float r0[4], r1[4];
    if (lane == 0) { r0[wave] = a0; r1[wave] = a1; }
    __syncthreads();
    if (tid == 0) {
        out[b * 2 + 0] = r0[0] + r0[1] + r0[2] + r0[3] + bfc[0];
        out[b * 2 + 1] = r1[0] + r1[1] + r1[2] + r1[3] + bfc[1];
    }
}

// ---------------------------------------------------------------------------
extern "C" void kernel_launch(void* const* d_in, const int* in_sizes, int n_in,
                              void* d_out, int out_size, void* d_ws, size_t ws_size,
                              hipStream_t stream) {
    const float* x_all    = (const float*)d_in[0];
    const float* supports = (const float*)d_in[1];
    const float* Wgl = (const float*)d_in[2];
    const float* Wa  = (const float*)d_in[3];
    const float* ba  = (const float*)d_in[4];
    const float* Wr  = (const float*)d_in[5];
    const float* br  = (const float*)d_in[6];
    const float* Wz  = (const float*)d_in[7];
    const float* bz  = (const float*)d_in[8];
    const float* Wh  = (const float*)d_in[9];
    const float* bh  = (const float*)d_in[10];
    const float* Wfc = (const float*)d_in[11];
    const float* bfc = (const float*)d_in[12];
    float* out = (float*)d_out;

    char* p = (char*)d_ws;
    auto alloc = [&](size_t bytes) { char* r = p; p += (bytes + 255) & ~(size_t)255; return r; };

    unsigned short* AttA = (unsigned short*)alloc((size_t)TT * BB * NN * NN * 2);  // 64 MB
    unsigned short* xh   = (unsigned short*)alloc((size_t)TT * BB * NN * DD * 2);  // 32 MB (f16)
    unsigned short* Afin = (unsigned short*)alloc((size_t)BB * NN * NN * 2);       // 4 MB
    unsigned short* hT0  = (unsigned short*)alloc((size_t)BB * DD * NN * 2);       // 2 MB
    unsigned short* hT1  = (unsigned short*)alloc((size_t)BB * DD * NN * 2);       // 2 MB
    unsigned short* WaT  = (unsigned short*)alloc(128 * 128 * 2);
    unsigned short* WrT  = (unsigned short*)alloc(256 * 128 * 2);
    unsigned short* WzT  = (unsigned short*)alloc(256 * 128 * 2);
    unsigned short* WhT  = (unsigned short*)alloc(256 * 128 * 2);
    // total ~104.5 MB

    // 1. f16 convert (live t) + GRU weight prep
    k_xw<<<TBLIVE + 128, 256, 0, stream>>>(x_all, Wa, Wr, Wz, Wh,
                                           xh, WaT, WrT, WzT, WhT);

    // 2. attention gram (in-block norms), live timesteps only
    k_gram2<<<4 * TBLIVE, 256, 0, stream>>>(xh, Wgl, AttA);

    // 3. scan + hTinit (merged)
    const float* x15 = x_all + (size_t)15 * BB * NN * DD;
    k_scanh<<<2048 + 1024, 256, 0, stream>>>(supports, AttA, x15, Afin, hT0);

    // 4-8. GRU steps (t=15 only)
    const unsigned short* hT_in = hT0;
    for (int s = 0; s < NSTEPS; ++s) {
        unsigned short* hTo = (s & 1) ? hT0 : hT1;
        k_step<<<8 * BB, 256, 0, stream>>>(Afin, hT_in,
                                           WaT, ba, WrT, br, WzT, bz, WhT, bh,
                                           hTo);
        hT_in = hTo;
    }

    // 9. fc (grid 32, direct write)
    k_fc<<<BB, 256, 0, stream>>>(hT1, Wfc, bfc, out);
}

// Round 11
// 295.887 us; speedup vs baseline: 1.0323x; 1.0323x over previous
//
#include <hip/hip_runtime.h>
#include <math.h>

#define TT 16
#define BB 32
#define NN 256
#define DD 128
#define NSTEPS 5
#define SKIPF 0.3f
#define EPSF 1e-8f
// truncated scan: timesteps t < T0 contribute <= ~2e-5 to A_15 (attn rows
// normalized) -- 400x below tolerance. Verified R18: absmax unchanged.
#define T0 7
#define TBLIVE ((TT - T0) * BB)    // 288 live (t,b) pairs
#define IVSTR 257                  // ivS h-stride (257%32==1 -> conflict-free-ish)

// R12: f16 packed gram. R15: 64x64 tiles. R17: FAILED cross-XCD barriers
// (45us each). R18: truncated scan: 304.8us. R19: dispatch compression =
// NEUTRAL -> boundaries are ~free; BUT in-block norms' ivS write was a
// 16-way bank conflict (2.84M, gram2 91->95.4us).
// R20 (this round):
//   a. ivS stride 257 (fix 16-way conflict on norms write).
//   b. gram2 reads f32 x directly, pkrtz in-register while loading frags;
//      the 57MB convert pass + xh buffer DELETED. wprep -> scanh spare blocks.
//   c. fc reverted to verified R16 512-block atomic version (R19's grid-32
//      used 12% of the machine).

typedef __attribute__((ext_vector_type(8))) short bf16x8;
typedef __attribute__((ext_vector_type(4))) float f32x4;
typedef __attribute__((ext_vector_type(8))) _Float16 half8;
typedef __attribute__((ext_vector_type(2))) _Float16 h2;

__device__ __forceinline__ unsigned short f2bf(float f) {
    union { float f; unsigned u; } v; v.f = f;
    unsigned r = (v.u + 0x7FFF + ((v.u >> 16) & 1)) >> 16;
    return (unsigned short)r;
}
__device__ __forceinline__ float bf2f(unsigned short u) {
    union { unsigned u; float f; } v; v.u = ((unsigned)u) << 16; return v.f;
}
__device__ __forceinline__ unsigned pack2(unsigned short a, unsigned short b) {
    return (unsigned)a | ((unsigned)b << 16);
}
// packed f32->f16 convert (RTZ), 1 inst for 2 elems
__device__ __forceinline__ unsigned pkrtz(float a, float b) {
    unsigned r;
    asm("v_cvt_pkrtz_f16_f32 %0, %1, %2" : "=v"(r) : "v"(a), "v"(b));
    return r;
}
__device__ __forceinline__ h2 u2h(unsigned u) {
    union { unsigned u; h2 h; } v; v.u = u; return v.h;
}
__device__ __forceinline__ float sigmoidf_(float x) {
    return 1.0f / (1.0f + __expf(-x));
}
__device__ __forceinline__ float tanhf_(float x) {
    return 1.0f - 2.0f / (__expf(2.0f * x) + 1.0f);
}
// load 8 f32 at src, convert to packed f16 half8
__device__ __forceinline__ half8 ld8f32h(const float* src) {
    float4 a = *(const float4*)src;
    float4 b = *(const float4*)(src + 4);
    uint4 o;
    o.x = pkrtz(a.x, a.y); o.y = pkrtz(a.z, a.w);
    o.z = pkrtz(b.x, b.y); o.w = pkrtz(b.z, b.w);
    union { uint4 u; half8 h; } v; v.u = o; return v.h;
}

// ---------------------------------------------------------------------------
// gram2 (f16 packed, 64x64 wave tiles, in-block norms, f32 direct input):
//   attn_t = 0.7*rownorm(relu(sum_h D_h X W2_h X^T D_h)).
// grid = 4 rg x TBLIVE = 1152 blocks, 256 threads, LDS ~21.5 KB.
// Frags converted f32->f16 in-register at load (ld8f32h); no xh buffer.
// ivS h-stride = 257 u32: norms write (stride-257 per m16) lands on
// distinct banks (257%32==1); h-loop reads consecutive -> conflict-free.
// ---------------------------------------------------------------------------
__global__ __launch_bounds__(256, 2) void k_gram2(const float* __restrict__ x,
                                                  const float* __restrict__ Wgl,
                                                  unsigned short* __restrict__ attn) {
    int bid = blockIdx.x;
    int rg = bid / TBLIVE;              // 0..3
    int tb = T0 * BB + (bid - rg * TBLIVE);
    int n0 = rg << 6;
    int tid = threadIdx.x;
    int wave = tid >> 6, lane = tid & 63;
    int m16 = lane & 15, quad = lane >> 4;
    int wcol = wave << 6;

    __shared__ unsigned wS[16 * 64];        // 4 KB: w^2 packed f16 pairs [h][d/2]
    __shared__ unsigned ivS[16 * IVSTR];    // 16.4 KB: invn dup-f16 [h*257 + n]
    __shared__ float rsum[4][64];           // 1 KB

    const float* Xb = x + ((size_t)tb << 15);

    // ---- stage wS = f16(w^2) from Wgl (one-time, 4 u32/thread) ----
    #pragma unroll
    for (int k = 0; k < 4; ++k) {
        int idx = (tid << 2) + k;        // 0..1023 ; h = idx>>6, j = idx&63
        float2 wv = *(const float2*)(Wgl + ((idx >> 6) << 7) + ((idx & 63) << 1));
        wS[idx] = pkrtz(wv.x * wv.x, wv.y * wv.y);
    }

    // ---- resident raw fragments (packed f16, converted from f32 at load) ----
    half8 Bf[4][4];                     // [ks][cb] = 64 VGPR (wave's 64 cols)
    #pragma unroll
    for (int ks = 0; ks < 4; ++ks)
        #pragma unroll
        for (int cb = 0; cb < 4; ++cb)
            Bf[ks][cb] = ld8f32h(Xb + ((wcol + (cb << 4) + m16) << 7) + (ks << 5) + (quad << 3));

    half8 Af[4][4];                     // [rb][ks] = 64 VGPR (block's 64 rows)
    #pragma unroll
    for (int rb = 0; rb < 4; ++rb)
        #pragma unroll
        for (int ks = 0; ks < 4; ++ks)
            Af[rb][ks] = ld8f32h(Xb + ((n0 + (rb << 4) + m16) << 7) + (ks << 5) + (quad << 3));

    f32x4 att[4][4];
    #pragma unroll
    for (int rb = 0; rb < 4; ++rb)
        #pragma unroll
        for (int cb = 0; cb < 4; ++cb) att[rb][cb] = (f32x4){0.f, 0.f, 0.f, 0.f};

    __syncthreads();   // wS staged

    union H8 { half8 v; h2 p[4]; };

    // ---- in-block norms for this wave's 64 cols (MFMA: x^2 vs w^2) ----
    {
        half8 w2f[4];
        #pragma unroll
        for (int ks = 0; ks < 4; ++ks)
            w2f[ks] = *(const half8*)((const unsigned short*)wS + (m16 << 7) + (ks << 5) + (quad << 3));
        #pragma unroll
        for (int cb = 0; cb < 4; ++cb) {
            f32x4 nacc = (f32x4){0.f, 0.f, 0.f, 0.f};
            #pragma unroll
            for (int ks = 0; ks < 4; ++ks) {
                H8 bb; bb.v = Bf[ks][cb];
                H8 sq;
                sq.p[0] = bb.p[0] * bb.p[0];
                sq.p[1] = bb.p[1] * bb.p[1];
                sq.p[2] = bb.p[2] * bb.p[2];
                sq.p[3] = bb.p[3] * bb.p[3];
                nacc = __builtin_amdgcn_mfma_f32_16x16x32_f16(sq.v, w2f[ks], nacc, 0, 0, 0);
            }
            #pragma unroll
            for (int r = 0; r < 4; ++r) {
                float inv = 1.0f / (sqrtf(nacc[r]) + EPSF);
                ivS[m16 * IVSTR + wcol + (cb << 4) + (quad << 2) + r] = pkrtz(inv, inv);
            }
        }
    }
    __syncthreads();   // ivS ready

    #pragma unroll 1
    for (int h = 0; h < 16; ++h) {
        const unsigned* ivh = ivS + h * IVSTR;
        h2 ivr[4], ivc[4];
        #pragma unroll
        for (int rb = 0; rb < 4; ++rb) ivr[rb] = u2h(ivh[n0 + (rb << 4) + m16]);
        #pragma unroll
        for (int cb = 0; cb < 4; ++cb) ivc[cb] = u2h(ivh[wcol + (cb << 4) + m16]);

        #pragma unroll
        for (int ks = 0; ks < 4; ++ks) {
            uint4 wu = *(const uint4*)(wS + (h << 6) + (ks << 4) + (quad << 2));
            h2 w0 = u2h(wu.x), w1 = u2h(wu.y), w2 = u2h(wu.z), w3 = u2h(wu.w);

            H8 afr[4];
            #pragma unroll
            for (int rb = 0; rb < 4; ++rb) {
                H8 a; a.v = Af[rb][ks];
                h2 s = ivr[rb];
                afr[rb].p[0] = a.p[0] * (w0 * s);
                afr[rb].p[1] = a.p[1] * (w1 * s);
                afr[rb].p[2] = a.p[2] * (w2 * s);
                afr[rb].p[3] = a.p[3] * (w3 * s);
            }
            #pragma unroll
            for (int cb = 0; cb < 4; ++cb) {
                H8 b; b.v = Bf[ks][cb];
                H8 bf;
                bf.p[0] = b.p[0] * ivc[cb];
                bf.p[1] = b.p[1] * ivc[cb];
                bf.p[2] = b.p[2] * ivc[cb];
                bf.p[3] = b.p[3] * ivc[cb];
                #pragma unroll
                for (int rb = 0; rb < 4; ++rb)
                    att[rb][cb] = __builtin_amdgcn_mfma_f32_16x16x32_f16(afr[rb].v, bf.v, att[rb][cb], 0, 0, 0);
            }
        }
    }

    // relu + rowsum + normalize (x0.7) -> bf16 attn  (relu(S)/16 trick: +16eps)
    float rs[4][4];
    #pragma unroll
    for (int rb = 0; rb < 4; ++rb)
        #pragma unroll
        for (int r = 0; r < 4; ++r) {
            float s = 0.f;
            #pragma unroll
            for (int cb = 0; cb < 4; ++cb) {
                float v = fmaxf(att[rb][cb][r], 0.0f);
                att[rb][cb][r] = v;
                s += v;
            }
            rs[rb][r] = s;
        }
    #pragma unroll
    for (int m = 1; m < 16; m <<= 1)
        #pragma unroll
        for (int rb = 0; rb < 4; ++rb)
            #pragma unroll
            for (int r = 0; r < 4; ++r)
                rs[rb][r] += __shfl_xor(rs[rb][r], m, 64);
    if (m16 == 0) {
        #pragma unroll
        for (int rb = 0; rb < 4; ++rb)
            #pragma unroll
            for (int r = 0; r < 4; ++r)
                rsum[wave][(rb << 4) + (quad << 2) + r] = rs[rb][r];
    }
    __syncthreads();

    unsigned short* outb = attn + ((size_t)tb << 16);
    #pragma unroll
    for (int rb = 0; rb < 4; ++rb) {
        #pragma unroll
        for (int r = 0; r < 4; ++r) {
            int row = (rb << 4) + (quad << 2) + r;
            float tot = rsum[0][row] + rsum[1][row] + rsum[2][row] + rsum[3][row];
            float inv = (1.0f - SKIPF) / (tot + 16.0f * EPSF);
            #pragma unroll
            for (int cb = 0; cb < 4; ++cb) {
                int col = wcol + (cb << 4) + m16;
                outb[((size_t)(n0 + row) << 8) + col] = f2bf(att[rb][cb][r] * inv);
            }
        }
    }
}

// ---------------------------------------------------------------------------
// scanh: blocks 0..2047:     truncated scan -> Afin bf16.
//        blocks 2048..3071:  hTinit transpose.
//        blocks 3072..3199:  bf16-transposed GRU weights (wprep).
// ---------------------------------------------------------------------------
__global__ __launch_bounds__(256) void k_scanh(const float* __restrict__ supports,
                                               const unsigned short* __restrict__ AttA,
                                               const float* __restrict__ x15,
                                               const float* __restrict__ Wa,
                                               const float* __restrict__ Wr,
                                               const float* __restrict__ Wz,
                                               const float* __restrict__ Wh,
                                               unsigned short* __restrict__ Afin,
                                               unsigned short* __restrict__ hT,
                                               unsigned short* __restrict__ WaT,
                                               unsigned short* __restrict__ WrT,
                                               unsigned short* __restrict__ WzT,
                                               unsigned short* __restrict__ WhT) {
    __shared__ float tl[32][33];
    int bid = blockIdx.x;
    int tid = threadIdx.x;
    if (bid < 2048) {
        size_t flat = ((size_t)bid * 256 + tid) * 4;
        float4 s4 = *(const float4*)(supports + flat);
        const float s7 = SKIPF * SKIPF * SKIPF * SKIPF * SKIPF * SKIPF * SKIPF; // 0.3^T0
        float a0 = s4.x * s7, a1 = s4.y * s7, a2 = s4.z * s7, a3 = s4.w * s7;
        #pragma unroll
        for (int t = T0; t < TT; ++t) {
            const unsigned short* p = AttA + ((size_t)t << 21) + flat;
            uint2 u = *(const uint2*)p;
            a0 = SKIPF * a0 + bf2f((unsigned short)(u.x & 0xffff));
            a1 = SKIPF * a1 + bf2f((unsigned short)(u.x >> 16));
            a2 = SKIPF * a2 + bf2f((unsigned short)(u.y & 0xffff));
            a3 = SKIPF * a3 + bf2f((unsigned short)(u.y >> 16));
        }
        uint2 o;
        o.x = pack2(f2bf(a0), f2bf(a1));
        o.y = pack2(f2bf(a2), f2bf(a3));
        *(uint2*)(Afin + flat) = o;
    } else if (bid < 3072) {
        int b2 = bid - 2048;
        int b = b2 >> 5; int r = b2 & 31; int d0 = (r >> 3) << 5; int n0 = (r & 7) << 5;
        int i = tid >> 5, j = tid & 31;
        #pragma unroll
        for (int s = 0; s < 4; ++s) {
            int nl = (s << 3) + i;
            tl[nl][j] = x15[((size_t)(b * 256 + n0 + nl) << 7) + d0 + j];
        }
        __syncthreads();
        #pragma unroll
        for (int s = 0; s < 4; ++s) {
            int dd = (s << 3) + i;
            hT[((size_t)(b * 128 + d0 + dd) << 8) + n0 + j] = f2bf(tl[j][dd]);
        }
    } else {
        int idx = (bid - 3072) * 256 + tid;     // 0..32767
        if (idx < 16384) {
            int dout = idx >> 7, din = idx & 127;
            WaT[idx] = f2bf(Wa[(din << 7) + dout]);
        }
        {
            int dout = idx >> 8, dk = idx & 255;
            WrT[idx] = f2bf(Wr[(dk << 7) + dout]);
            WzT[idx] = f2bf(Wz[(dk << 7) + dout]);
            WhT[idx] = f2bf(Wh[(dk << 7) + dout]);
        }
    }
}

// ---------------------------------------------------------------------------
// step: fused GGNN/GRU step for t=15 only — VERIFIED R16 version.
// grid = 8 rg x 32 b = 256 blocks.
// ---------------------------------------------------------------------------
__global__ __launch_bounds__(256) void k_step(
    const unsigned short* __restrict__ Afin,
    const unsigned short* __restrict__ hT,
    const unsigned short* __restrict__ WaT, const float* __restrict__ ba,
    const unsigned short* __restrict__ WrT, const float* __restrict__ br,
    const unsigned short* __restrict__ WzT, const float* __restrict__ bz,
    const unsigned short* __restrict__ WhT, const float* __restrict__ bh,
    unsigned short* __restrict__ hT_o) {

    int bid = blockIdx.x;
    int b = bid & 31, rg = bid >> 5;
    int n0 = rg << 5;
    int tid = threadIdx.x;
    int wave = tid >> 6, lane = tid & 63;
    int m16 = lane & 15, quad = lane >> 4;
    int wcol = wave << 5;

    __shared__ unsigned short msgS[32 * 136];
    __shared__ unsigned short ahS[32 * 264];   // k 0..127 = a, 128..255 = h (later r*h)

    const unsigned short* hTb = hT + ((size_t)b << 15);

    // stage h-half of ahS from hT (transpose: ahS[row][128+d] = hT[d][n0+row])
    #pragma unroll
    for (int j = 0; j < 16; ++j) {
        int idx = (j << 8) + tid;            // 0..4095
        int d = idx >> 5, row = idx & 31;
        ahS[row * 264 + 128 + d] = hTb[((size_t)d << 8) + n0 + row];
    }

    // ---- bmm: msg = A_tile @ h  (K=256) ----
    f32x4 acc[2][2];
    #pragma unroll
    for (int rb = 0; rb < 2; ++rb)
        #pragma unroll
        for (int cb = 0; cb < 2; ++cb) acc[rb][cb] = (f32x4){0.f, 0.f, 0.f, 0.f};

    const unsigned short* Ab = Afin + ((size_t)b << 16) + ((size_t)n0 << 8);
    #pragma unroll 2
    for (int ks = 0; ks < 8; ++ks) {
        bf16x8 af[2], bf[2];
        #pragma unroll
        for (int rb = 0; rb < 2; ++rb)
            af[rb] = *(const bf16x8*)(Ab + (((rb << 4) + m16) << 8) + (ks << 5) + (quad << 3));
        #pragma unroll
        for (int cb = 0; cb < 2; ++cb)
            bf[cb] = *(const bf16x8*)(hTb + ((wcol + (cb << 4) + m16) << 8) + (ks << 5) + (quad << 3));
        #pragma unroll
        for (int rb = 0; rb < 2; ++rb)
            #pragma unroll
            for (int cb = 0; cb < 2; ++cb)
                acc[rb][cb] = __builtin_amdgcn_mfma_f32_16x16x32_bf16(af[rb], bf[cb], acc[rb][cb], 0, 0, 0);
    }
    #pragma unroll
    for (int rb = 0; rb < 2; ++rb)
        #pragma unroll
        for (int cb = 0; cb < 2; ++cb)
            #pragma unroll
            for (int r = 0; r < 4; ++r)
                msgS[((rb << 4) + (quad << 2) + r) * 136 + wcol + (cb << 4) + m16] = f2bf(acc[rb][cb][r]);
    __syncthreads();   // covers h-half staging too

    // ---- a = msg @ Wa + ba ----
    #pragma unroll
    for (int rb = 0; rb < 2; ++rb)
        #pragma unroll
        for (int cb = 0; cb < 2; ++cb) acc[rb][cb] = (f32x4){0.f, 0.f, 0.f, 0.f};
    #pragma unroll
    for (int ks = 0; ks < 4; ++ks) {
        bf16x8 af[2], bf[2];
        #pragma unroll
        for (int rb = 0; rb < 2; ++rb)
            af[rb] = *(const bf16x8*)(msgS + ((rb << 4) + m16) * 136 + (ks << 5) + (quad << 3));
        #pragma unroll
        for (int cb = 0; cb < 2; ++cb)
            bf[cb] = *(const bf16x8*)(WaT + ((wcol + (cb << 4) + m16) << 7) + (ks << 5) + (quad << 3));
        #pragma unroll
        for (int rb = 0; rb < 2; ++rb)
            #pragma unroll
            for (int cb = 0; cb < 2; ++cb)
                acc[rb][cb] = __builtin_amdgcn_mfma_f32_16x16x32_bf16(af[rb], bf[cb], acc[rb][cb], 0, 0, 0);
    }
    {
        float bav[2];
        #pragma unroll
        for (int cb = 0; cb < 2; ++cb) bav[cb] = ba[wcol + (cb << 4) + m16];
        #pragma unroll
        for (int rb = 0; rb < 2; ++rb)
            #pragma unroll
            for (int cb = 0; cb < 2; ++cb)
                #pragma unroll
                for (int r = 0; r < 4; ++r)
                    ahS[((rb << 4) + (quad << 2) + r) * 264 + wcol + (cb << 4) + m16] =
                        f2bf(acc[rb][cb][r] + bav[cb]);
    }
    __syncthreads();

    // h_old (for r*h and final update): uint2 = 4 consecutive n at fixed col
    float hv[2][2][4];
    #pragma unroll
    for (int rb = 0; rb < 2; ++rb)
        #pragma unroll
        for (int cb = 0; cb < 2; ++cb) {
            int col = wcol + (cb << 4) + m16;
            uint2 u = *(const uint2*)(hTb + ((size_t)col << 8) + n0 + (rb << 4) + (quad << 2));
            hv[rb][cb][0] = bf2f((unsigned short)(u.x & 0xffff));
            hv[rb][cb][1] = bf2f((unsigned short)(u.x >> 16));
            hv[rb][cb][2] = bf2f((unsigned short)(u.y & 0xffff));
            hv[rb][cb][3] = bf2f((unsigned short)(u.y >> 16));
        }

    // ---- r and z ----
    f32x4 racc[2][2], zacc[2][2];
    #pragma unroll
    for (int rb = 0; rb < 2; ++rb)
        #pragma unroll
        for (int cb = 0; cb < 2; ++cb) {
            racc[rb][cb] = (f32x4){0.f, 0.f, 0.f, 0.f};
            zacc[rb][cb] = (f32x4){0.f, 0.f, 0.f, 0.f};
        }
    #pragma unroll 2
    for (int ks = 0; ks < 8; ++ks) {
        bf16x8 af[2], bfr[2], bfz[2];
        #pragma unroll
        for (int rb = 0; rb < 2; ++rb)
            af[rb] = *(const bf16x8*)(ahS + ((rb << 4) + m16) * 264 + (ks << 5) + (quad << 3));
        #pragma unroll
        for (int cb = 0; cb < 2; ++cb) {
            int dout = wcol + (cb << 4) + m16;
            bfr[cb] = *(const bf16x8*)(WrT + (dout << 8) + (ks << 5) + (quad << 3));
            bfz[cb] = *(const bf16x8*)(WzT + (dout << 8) + (ks << 5) + (quad << 3));
        }
        #pragma unroll
        for (int rb = 0; rb < 2; ++rb)
            #pragma unroll
            for (int cb = 0; cb < 2; ++cb) {
                racc[rb][cb] = __builtin_amdgcn_mfma_f32_16x16x32_bf16(af[rb], bfr[cb], racc[rb][cb], 0, 0, 0);
                zacc[rb][cb] = __builtin_amdgcn_mfma_f32_16x16x32_bf16(af[rb], bfz[cb], zacc[rb][cb], 0, 0, 0);
            }
    }
    float zv[2][2][4];
    {
        float brv[2], bzv[2];
        #pragma unroll
        for (int cb = 0; cb < 2; ++cb) {
            brv[cb] = br[wcol + (cb << 4) + m16];
            bzv[cb] = bz[wcol + (cb << 4) + m16];
        }
        #pragma unroll
        for (int rb = 0; rb < 2; ++rb)
            #pragma unroll
            for (int cb = 0; cb < 2; ++cb)
                #pragma unroll
                for (int r = 0; r < 4; ++r) {
                    racc[rb][cb][r] = sigmoidf_(racc[rb][cb][r] + brv[cb]);
                    zv[rb][cb][r]  = sigmoidf_(zacc[rb][cb][r] + bzv[cb]);
                }
    }
    __syncthreads();   // all ahS reads done -> safe to overwrite h-half

    #pragma unroll
    for (int rb = 0; rb < 2; ++rb)
        #pragma unroll
        for (int cb = 0; cb < 2; ++cb)
            #pragma unroll
            for (int r = 0; r < 4; ++r)
                ahS[((rb << 4) + (quad << 2) + r) * 264 + 128 + wcol + (cb << 4) + m16] =
                    f2bf(racc[rb][cb][r] * hv[rb][cb][r]);
    __syncthreads();

    // ---- h_tilde ----
    #pragma unroll
    for (int rb = 0; rb < 2; ++rb)
        #pragma unroll
        for (int cb = 0; cb < 2; ++cb) acc[rb][cb] = (f32x4){0.f, 0.f, 0.f, 0.f};
    #pragma unroll 2
    for (int ks = 0; ks < 8; ++ks) {
        bf16x8 af[2], bf[2];
        #pragma unroll
        for (int rb = 0; rb < 2; ++rb)
            af[rb] = *(const bf16x8*)(ahS + ((rb << 4) + m16) * 264 + (ks << 5) + (quad << 3));
        #pragma unroll
        for (int cb = 0; cb < 2; ++cb)
            bf[cb] = *(const bf16x8*)(WhT + ((wcol + (cb << 4) + m16) << 8) + (ks << 5) + (quad << 3));
        #pragma unroll
        for (int rb = 0; rb < 2; ++rb)
            #pragma unroll
            for (int cb = 0; cb < 2; ++cb)
                acc[rb][cb] = __builtin_amdgcn_mfma_f32_16x16x32_bf16(af[rb], bf[cb], acc[rb][cb], 0, 0, 0);
    }

    // ---- update + writes (hT only) ----
    {
        float bhv[2];
        #pragma unroll
        for (int cb = 0; cb < 2; ++cb) bhv[cb] = bh[wcol + (cb << 4) + m16];
        #pragma unroll
        for (int rb = 0; rb < 2; ++rb)
            #pragma unroll
            for (int cb = 0; cb < 2; ++cb) {
                int col = wcol + (cb << 4) + m16;
                unsigned short pk[4];
                #pragma unroll
                for (int r = 0; r < 4; ++r) {
                    float ht = tanhf_(acc[rb][cb][r] + bhv[cb]);
                    float hn = hv[rb][cb][r] + zv[rb][cb][r] * (ht - hv[rb][cb][r]);
                    pk[r] = f2bf(hn);
                }
                uint2 p;
                p.x = pack2(pk[0], pk[1]); p.y = pack2(pk[2], pk[3]);
                *(uint2*)(hT_o + ((size_t)(b * 128 + col) << 8) + n0 + (rb << 4) + (quad << 2)) = p;
            }
    }
}

// ---------------------------------------------------------------------------
// fc (VERIFIED R16): logits[b,c] = sum over col-major h + bfc. grid = 512.
// ---------------------------------------------------------------------------
__global__ __launch_bounds__(256) void k_fc(const unsigned short* __restrict__ hT,
                                            const float* __restrict__ Wfc,
                                            const float* __restrict__ bfc,
                                            float* __restrict__ out) {
    int bid = blockIdx.x;
    int b = bid >> 4, part = bid & 15;
    int tid = threadIdx.x;
    const unsigned short* hp = hT + ((size_t)b << 15);
    int i = part * 2048 + tid * 8;       // linear col-major: i = d*256 + n
    int d = i >> 8, n = i & 255;
    uint4 hu = *(const uint4*)(hp + i);
    unsigned short hs[8];
    hs[0] = hu.x & 0xffff; hs[1] = hu.x >> 16;
    hs[2] = hu.y & 0xffff; hs[3] = hu.y >> 16;
    hs[4] = hu.z & 0xffff; hs[5] = hu.z >> 16;
    hs[6] = hu.w & 0xffff; hs[7] = hu.w >> 16;
    float a0 = 0.f, a1 = 0.f;
    #pragma unroll
    for (int k = 0; k < 8; ++k) {
        float v = bf2f(hs[k]);
        const float2 w = *(const float2*)(Wfc + ((size_t)(n + k) * 128 + d) * 2);
        a0 = fmaf(v, w.x, a0);
        a1 = fmaf(v, w.y, a1);
    }
    int wave = tid >> 6, lane = tid & 63;
    #pragma unroll
    for (int off = 32; off; off >>= 1) {
        a0 += __shfl_down(a0, off, 64);
        a1 += __shfl_down(a1, off, 64);
    }
    __shared__ float r0[4], r1[4];
    if (lane == 0) { r0[wave] = a0; r1[wave] = a1; }
    __syncthreads();
    if (tid == 0) {
        float s0 = r0[0] + r0[1] + r0[2] + r0[3];
        float s1 = r1[0] + r1[1] + r1[2] + r1[3];
        if (part == 0) { s0 += bfc[0]; s1 += bfc[1]; }
        atomicAdd(&out[b * 2 + 0], s0);
        atomicAdd(&out[b * 2 + 1], s1);
    }
}

// ---------------------------------------------------------------------------
extern "C" void kernel_launch(void* const* d_in, const int* in_sizes, int n_in,
                              void* d_out, int out_size, void* d_ws, size_t ws_size,
                              hipStream_t stream) {
    const float* x_all    = (const float*)d_in[0];
    const float* supports = (const float*)d_in[1];
    const float* Wgl = (const float*)d_in[2];
    const float* Wa  = (const float*)d_in[3];
    const float* ba  = (const float*)d_in[4];
    const float* Wr  = (const float*)d_in[5];
    const float* br  = (const float*)d_in[6];
    const float* Wz  = (const float*)d_in[7];
    const float* bz  = (const float*)d_in[8];
    const float* Wh  = (const float*)d_in[9];
    const float* bh  = (const float*)d_in[10];
    const float* Wfc = (const float*)d_in[11];
    const float* bfc = (const float*)d_in[12];
    float* out = (float*)d_out;

    char* p = (char*)d_ws;
    auto alloc = [&](size_t bytes) { char* r = p; p += (bytes + 255) & ~(size_t)255; return r; };

    unsigned short* AttA = (unsigned short*)alloc((size_t)TT * BB * NN * NN * 2);  // 64 MB
    unsigned short* Afin = (unsigned short*)alloc((size_t)BB * NN * NN * 2);       // 4 MB
    unsigned short* hT0  = (unsigned short*)alloc((size_t)BB * DD * NN * 2);       // 2 MB
    unsigned short* hT1  = (unsigned short*)alloc((size_t)BB * DD * NN * 2);       // 2 MB
    unsigned short* WaT  = (unsigned short*)alloc(128 * 128 * 2);
    unsigned short* WrT  = (unsigned short*)alloc(256 * 128 * 2);
    unsigned short* WzT  = (unsigned short*)alloc(256 * 128 * 2);
    unsigned short* WhT  = (unsigned short*)alloc(256 * 128 * 2);
    // total ~72.5 MB

    // 1. attention gram (in-block norms, f32 direct), live timesteps only
    k_gram2<<<4 * TBLIVE, 256, 0, stream>>>(x_all, Wgl, AttA);

    // 2. scan + hTinit + wprep (merged)
    const float* x15 = x_all + (size_t)15 * BB * NN * DD;
    k_scanh<<<2048 + 1024 + 128, 256, 0, stream>>>(supports, AttA, x15,
                                                   Wa, Wr, Wz, Wh,
                                                   Afin, hT0,
                                                   WaT, WrT, WzT, WhT);

    // 3-7. GRU steps (t=15 only)
    const unsigned short* hT_in = hT0;
    for (int s = 0; s < NSTEPS; ++s) {
        unsigned short* hTo = (s & 1) ? hT0 : hT1;
        k_step<<<8 * BB, 256, 0, stream>>>(Afin, hT_in,
                                           WaT, ba, WrT, br, WzT, bz, WhT, bh,
                                           hTo);
        hT_in = hTo;
    }

    // 8. fc (parallel, atomic)
    hipMemsetAsync(d_out, 0, (size_t)out_size * sizeof(float), stream);
    k_fc<<<BB * 16, 256, 0, stream>>>(hT1, Wfc, bfc, out);
}